// Round 3
// baseline (405.119 us; speedup 1.0000x reference)
//
#include <hip/hip_runtime.h>
#include <hip/hip_bf16.h>

// Problem constants: B=4, S=4096, D=1024, R=64
#define M_TOT 16384   // B*S
#define DK    1024
#define RN    64
#define SQ_S  4096

typedef __attribute__((ext_vector_type(8))) short  short8;   // 8 bf16 (4 VGPRs)
typedef __attribute__((ext_vector_type(4))) float  f32x4;

__device__ __forceinline__ unsigned short f2bf(float f) {
    unsigned u = __float_as_uint(f);
    return (unsigned short)((u + 0x7fffu + ((u >> 16) & 1u)) >> 16);  // RNE
}
__device__ __forceinline__ float bf2f(unsigned short h) {
    return __uint_as_float((unsigned)h << 16);
}

// ---------------------------------------------------------------------------
// prep: proj [D][R] fp32  ->  projT_hi / projT_lo [R][D] bf16-bits
// ---------------------------------------------------------------------------
__global__ __launch_bounds__(256) void prep_kernel(
        const float* __restrict__ proj,
        unsigned short* __restrict__ pTh,
        unsigned short* __restrict__ pTl) {
    int idx = blockIdx.x * 256 + threadIdx.x;      // 0 .. R*D-1
    int r = idx >> 10;            // / DK
    int k = idx & 1023;           // % DK
    float v = proj[k * RN + r];
    unsigned short hi = f2bf(v);
    pTh[idx] = hi;
    pTl[idx] = f2bf(v - bf2f(hi));
}

// ---------------------------------------------------------------------------
// phase 1: p = x @ proj  (M=16384, K=1024, N=64), bf16 split-3 MFMA.
// K-split across the block's 4 waves (256 deep each) + LDS reduction.
// (validated round-2; ~15 us est.)
// ---------------------------------------------------------------------------
__global__ __launch_bounds__(256) void phase1_kernel(
        const float* __restrict__ x,
        const unsigned short* __restrict__ pTh,
        const unsigned short* __restrict__ pTl,
        unsigned short* __restrict__ p_hi,
        unsigned short* __restrict__ p_lo,
        float* __restrict__ sq) {
    const int tid  = threadIdx.x;
    const int wave = tid >> 6;
    const int lane = tid & 63;
    const int lr   = lane & 15;   // row within 16-tile (A) / col (B)
    const int lg   = lane >> 4;   // k-subgroup (8 elements each)

    const long m0    = (long)blockIdx.x * 16;
    const int  kbase = wave * 256;                 // this wave's K slice
    const float* xrow = x + (m0 + lr) * DK + kbase + lg * 8;

    f32x4 acc[4] = {f32x4{0,0,0,0}, f32x4{0,0,0,0}, f32x4{0,0,0,0}, f32x4{0,0,0,0}};

    #pragma unroll 2
    for (int kc = 0; kc < 8; ++kc) {
        f32x4 a0 = *(const f32x4*)(xrow + kc * 32);
        f32x4 a1 = *(const f32x4*)(xrow + kc * 32 + 4);
        short8 ah, al;
        #pragma unroll
        for (int i = 0; i < 4; ++i) {
            unsigned short h0 = f2bf(a0[i]);
            ah[i] = (short)h0;
            al[i] = (short)f2bf(a0[i] - bf2f(h0));
            unsigned short h1 = f2bf(a1[i]);
            ah[i + 4] = (short)h1;
            al[i + 4] = (short)f2bf(a1[i] - bf2f(h1));
        }
        #pragma unroll
        for (int cj = 0; cj < 4; ++cj) {
            long bo = (long)(cj * 16 + lr) * DK + kbase + kc * 32 + lg * 8;
            short8 bh = *(const short8*)(pTh + bo);
            short8 bl = *(const short8*)(pTl + bo);
            f32x4 c = acc[cj];
            c = __builtin_amdgcn_mfma_f32_16x16x32_bf16(ah, bh, c, 0, 0, 0);
            c = __builtin_amdgcn_mfma_f32_16x16x32_bf16(ah, bl, c, 0, 0, 0);
            c = __builtin_amdgcn_mfma_f32_16x16x32_bf16(al, bh, c, 0, 0, 0);
            acc[cj] = c;
        }
    }

    __shared__ float red[4][64][17];
    #pragma unroll
    for (int cj = 0; cj < 4; ++cj)
        #pragma unroll
        for (int j = 0; j < 4; ++j)
            red[wave][lane][cj * 4 + j] = acc[cj][j];
    __syncthreads();

    if (wave == 0) {
        #pragma unroll
        for (int j = 0; j < 4; ++j) {
            const long m = m0 + lg * 4 + j;
            float ssum = 0.f;
            #pragma unroll
            for (int cj = 0; cj < 4; ++cj) {
                const int sl = cj * 4 + j;
                float v = red[0][lane][sl] + red[1][lane][sl]
                        + red[2][lane][sl] + red[3][lane][sl];
                unsigned short hi = f2bf(v);
                p_hi[m * RN + cj * 16 + lr] = hi;
                p_lo[m * RN + cj * 16 + lr] = f2bf(v - bf2f(hi));
                ssum += v * v;
            }
            ssum += __shfl_xor(ssum, 1);
            ssum += __shfl_xor(ssum, 2);
            ssum += __shfl_xor(ssum, 4);
            ssum += __shfl_xor(ssum, 8);
            if (lr == 0) sq[m] = ssum;
        }
    }
}

// ---------------------------------------------------------------------------
// phase 2: per batch, dist[s,t] = relu(sq[s]+sq[t] - 2 * p[s].p[t])
// NEW: 512 threads / 8 waves per 128x128 tile; each wave owns 32s x 64t.
//   acc 32 VGPR (was 64), peak live regs ~100 (was ~215) -> ~4 waves/SIMD.
//   Plain stores (drop nontemporal), bijective XCD swizzle (nwg%8==0).
// ---------------------------------------------------------------------------
__global__ __launch_bounds__(512) void phase2_kernel(
        const unsigned short* __restrict__ p_hi,
        const unsigned short* __restrict__ p_lo,
        const float* __restrict__ sq,
        float* __restrict__ out) {
    // XCD-aware bijective swizzle: 4096 wgs, 512 per XCD chunk (m204 form).
    const int wg = (blockIdx.x & 7) * 512 + (blockIdx.x >> 3);
    const int b      = wg >> 10;          // / 1024 tiles per batch
    const int r      = wg & 1023;
    const long s0 = (long)(r >> 5) * 128; // 32 t-tiles fastest
    const long t0 = (long)(r & 31) * 128;

    const int tid  = threadIdx.x;
    const int wave = tid >> 6;
    const int lane = tid & 63;
    const int sstrip = wave >> 1;         // 0..3 : which 32-row s strip
    const int thalf  = wave & 1;          // 0..1 : which 64-col t half
    const int lr = lane & 15, lg = lane >> 4;

    const unsigned short* ph  = p_hi + (long)b * SQ_S * RN;
    const unsigned short* pl  = p_lo + (long)b * SQ_S * RN;
    const float*          sqb = sq   + (long)b * SQ_S;

    f32x4 acc[4][2];   // [ai: t-tile 0..3][bj: s-tile 0..1]
    #pragma unroll
    for (int i = 0; i < 4; ++i) {
        acc[i][0] = f32x4{0, 0, 0, 0};
        acc[i][1] = f32x4{0, 0, 0, 0};
    }

    const long tbase = t0 + thalf * 64;       // wave's t rows (A operand)
    const long sbase = s0 + sstrip * 32;      // wave's s rows (B operand)

    #pragma unroll
    for (int kc = 0; kc < 2; ++kc) {
        short8 th_[4], tl_[4], sh_[2], sl_[2];
        #pragma unroll
        for (int i = 0; i < 4; ++i) {
            long ao = (tbase + i * 16 + lr) * RN + kc * 32 + lg * 8;
            th_[i] = *(const short8*)(ph + ao);
            tl_[i] = *(const short8*)(pl + ao);
        }
        #pragma unroll
        for (int i = 0; i < 2; ++i) {
            long bo = (sbase + i * 16 + lr) * RN + kc * 32 + lg * 8;
            sh_[i] = *(const short8*)(ph + bo);
            sl_[i] = *(const short8*)(pl + bo);
        }
        #pragma unroll
        for (int ai = 0; ai < 4; ++ai)
            #pragma unroll
            for (int bj = 0; bj < 2; ++bj) {
                f32x4 c = acc[ai][bj];
                c = __builtin_amdgcn_mfma_f32_16x16x32_bf16(th_[ai], sh_[bj], c, 0, 0, 0);
                c = __builtin_amdgcn_mfma_f32_16x16x32_bf16(th_[ai], sl_[bj], c, 0, 0, 0);
                c = __builtin_amdgcn_mfma_f32_16x16x32_bf16(tl_[ai], sh_[bj], c, 0, 0, 0);
                acc[ai][bj] = c;
            }
    }

    // Epilogue: dist = relu(sq_s + sq_t - 2*cross), dwordx4 stores.
    // C/D layout (m89): col(lane&15) = B index (s), row(lg*4+j) = A index (t).
    f32x4 sqt[4];
    #pragma unroll
    for (int ai = 0; ai < 4; ++ai)
        sqt[ai] = *(const f32x4*)(sqb + tbase + ai * 16 + lg * 4);

    float* outb = out + (long)b * SQ_S * SQ_S;
    #pragma unroll
    for (int bj = 0; bj < 2; ++bj) {
        const long s = sbase + bj * 16 + lr;
        const float sqs = sqb[s];
        float* orow = outb + s * SQ_S + tbase;
        #pragma unroll
        for (int ai = 0; ai < 4; ++ai) {
            f32x4 v;
            #pragma unroll
            for (int j = 0; j < 4; ++j)
                v[j] = fmaxf(sqs + sqt[ai][j] - 2.0f * acc[ai][bj][j], 0.0f);
            *(f32x4*)(orow + ai * 16 + lg * 4) = v;
        }
    }
}

// ---------------------------------------------------------------------------
extern "C" void kernel_launch(void* const* d_in, const int* in_sizes, int n_in,
                              void* d_out, int out_size, void* d_ws, size_t ws_size,
                              hipStream_t stream) {
    const float* x    = (const float*)d_in[0];   // [B,S,D] fp32
    const float* proj = (const float*)d_in[1];   // [D,R]  fp32
    float* out = (float*)d_out;                  // [B,S,S] fp32

    // Workspace layout (all 16B-aligned):
    //   projT_hi: R*D ushort = 128 KiB
    //   projT_lo: R*D ushort = 128 KiB
    //   p_hi:     M*R ushort = 2 MiB
    //   p_lo:     M*R ushort = 2 MiB
    //   sq:       M float    = 64 KiB
    unsigned short* pTh  = (unsigned short*)d_ws;
    unsigned short* pTl  = pTh + RN * DK;
    unsigned short* p_hi = pTl + RN * DK;
    unsigned short* p_lo = p_hi + (long)M_TOT * RN;
    float*          sqp  = (float*)(p_lo + (long)M_TOT * RN);

    prep_kernel<<<(RN * DK) / 256, 256, 0, stream>>>(proj, pTh, pTl);
    phase1_kernel<<<M_TOT / 16, 256, 0, stream>>>(x, pTh, pTl, p_hi, p_lo, sqp);
    phase2_kernel<<<dim3(4096), 512, 0, stream>>>(p_hi, p_lo, sqp, out);
}